// Round 9
// baseline (418.203 us; speedup 1.0000x reference)
//
#include <hip/hip_runtime.h>

constexpr int NE = 8192;
constexpr int ED = 256;
constexpr int BS = 32768;
constexpr float DELTA = 4e-4f;   // >> 2*(bf16-MFMA err) + np-grid + key-quantization (~7.6e-6)

typedef short bf16x8 __attribute__((ext_vector_type(8)));
typedef float f32x4 __attribute__((ext_vector_type(4)));

#define GLOAD_LDS16(g, l) __builtin_amdgcn_global_load_lds( \
    (const __attribute__((address_space(1))) void*)(g),     \
    (__attribute__((address_space(3))) void*)(l), 16, 0, 0)

__device__ __forceinline__ short f2bf(float f) {            // RNE f32 -> bf16
    unsigned u = __float_as_uint(f);
    u = u + 0x7FFFu + ((u >> 16) & 1u);
    return (short)(u >> 16);
}
__device__ __forceinline__ unsigned bf16_rd(float x) {      // round toward -inf -> bf16 bits
    unsigned u = __float_as_uint(x);
    unsigned h = u >> 16;
    if ((u & 0x80000000u) && (u & 0xFFFFu)) ++h;
    return h;
}
__device__ __forceinline__ unsigned umn(unsigned a, unsigned b) { return a < b ? a : b; }
__device__ __forceinline__ unsigned umx(unsigned a, unsigned b) { return a > b ? a : b; }

// ---------- np-exact pairwise ||row||^2 (verified bit-exact vs np.sum in R2) ----------
// out5 (optional): +0.5 biased copy for pass1 keys.
__global__ void sq_np_kernel(const float* __restrict__ a, float* __restrict__ out,
                             float* __restrict__ out5) {
    int gtid = blockIdx.x * blockDim.x + threadIdx.x;
    int wave = gtid >> 6;
    int lane = threadIdx.x & 63;
    int sub  = lane & 7;
    int row  = wave * 8 + (lane >> 3);
    const float* p = a + (size_t)row * ED;
    float b0 = 0.f, b1 = 0.f;
#pragma unroll
    for (int t = 0; t < 16; ++t) { float v = p[8 * t + sub];       b0 = __fadd_rn(b0, __fmul_rn(v, v)); }
#pragma unroll
    for (int t = 0; t < 16; ++t) { float v = p[128 + 8 * t + sub]; b1 = __fadd_rn(b1, __fmul_rn(v, v)); }
    b0 = __fadd_rn(b0, __shfl_xor(b0, 1));
    b0 = __fadd_rn(b0, __shfl_xor(b0, 2));
    b0 = __fadd_rn(b0, __shfl_xor(b0, 4));
    b1 = __fadd_rn(b1, __shfl_xor(b1, 1));
    b1 = __fadd_rn(b1, __shfl_xor(b1, 2));
    b1 = __fadd_rn(b1, __shfl_xor(b1, 4));
    float tot = __fadd_rn(b0, b1);
    if (sub == 0) {
        out[row] = tot;
        if (out5) out5[row] = tot + 0.5f;
    }
}

// ---------- convert e (f32) -> eb (bf16), row-major, once ----------
__global__ void cvt_bf16_kernel(const float* __restrict__ a, short* __restrict__ o) {
    int i = blockIdx.x * blockDim.x + threadIdx.x;     // one per 8 elements
    const float4* p = reinterpret_cast<const float4*>(a + (size_t)i * 8);
    float4 v0 = p[0], v1 = p[1];
    bf16x8 h;
    h[0] = f2bf(v0.x); h[1] = f2bf(v0.y); h[2] = f2bf(v0.z); h[3] = f2bf(v0.w);
    h[4] = f2bf(v1.x); h[5] = f2bf(v1.y); h[6] = f2bf(v1.z); h[7] = f2bf(v1.w);
    *reinterpret_cast<bf16x8*>(o + (size_t)i * 8) = h;
}

// ---------- pass 1: swapped-operand MFMA (D = e·z^T), j=4 reg z-rows, top-2 epilogue ----------
// 4 waves x 64 z-rows = 256 rows/block; col-quarter (2048 cols) = 32 tiles of 64.
// acc: col(lane&15) = z-row, row(lg*4+reg) = e-col -> argmin axis in registers.
__global__ __launch_bounds__(256, 2) void vq_pass1(
        const float* __restrict__ z, const char* __restrict__ eb,
        const float* __restrict__ e2p, uint2* __restrict__ wsp) {
    __shared__ __align__(16) char Bs[2][32768];      // e-tiles: 64 cols x 512 B (swizzled)

    const int tid  = threadIdx.x;
    const int wid  = tid >> 6, lane = tid & 63;
    const int l15  = lane & 15, lg = lane >> 4;
    const int kblk = blockIdx.x;
    const int rg   = (kblk & 7) | ((kblk >> 5) << 3);   // row-group: quarters share XCD
    const int q    = (kblk >> 3) & 3;
    const int brow = rg * 256;
    const int c0q  = q * 2048;
    const int wr0  = brow + wid * 64;
    const int swz  = (l15 & 7) << 4;

    // ---- prologue: stage tile 0 ----
#pragma unroll
    for (int it = 0; it < 8; ++it) {
        int slot = it * 256 + tid;                   // 0..2047 = 64 cols x 32 16B-units
        int c = slot >> 5, m = slot & 31;
        GLOAD_LDS16(eb + (size_t)(c0q + c) * 512 + ((m ^ (c & 7)) << 4),
                    &Bs[0][slot * 16]);
    }
    // ---- z rows -> registers (bf16), 64 rows/wave ----
    bf16x8 zreg[4][8];
#pragma unroll
    for (int j = 0; j < 4; ++j) {
        const float* zr = z + (size_t)(wr0 + j * 16 + l15) * ED + lg * 8;
#pragma unroll
        for (int t8 = 0; t8 < 8; ++t8) {
            float4 v0 = *reinterpret_cast<const float4*>(zr + t8 * 32);
            float4 v1 = *reinterpret_cast<const float4*>(zr + t8 * 32 + 4);
            bf16x8 h;
            h[0] = f2bf(v0.x); h[1] = f2bf(v0.y); h[2] = f2bf(v0.z); h[3] = f2bf(v0.w);
            h[4] = f2bf(v1.x); h[5] = f2bf(v1.y); h[6] = f2bf(v1.z); h[7] = f2bf(v1.w);
            zreg[j][t8] = h;
        }
    }

    unsigned rk1[4], rk2[4];
#pragma unroll 2
    for (int t = 0; t < 32; ++t) {
        const int buf = t & 1;
        __syncthreads();                 // drains vmcnt(0): tile t staged; prev reads done
        if (t < 31) {                    // prefetch next tile into other buffer
            const char* src = eb + (size_t)(c0q + (t + 1) * 64) * 512;
#pragma unroll
            for (int it = 0; it < 8; ++it) {
                int slot = it * 256 + tid;
                int c = slot >> 5, m = slot & 31;
                GLOAD_LDS16(src + (size_t)c * 512 + ((m ^ (c & 7)) << 4),
                            &Bs[buf ^ 1][slot * 16]);
            }
        }

        f32x4 acc[4][4];
#pragma unroll
        for (int i = 0; i < 4; ++i)
#pragma unroll
            for (int j = 0; j < 4; ++j) acc[i][j] = (f32x4){0.f, 0.f, 0.f, 0.f};

#pragma unroll
        for (int t8 = 0; t8 < 8; ++t8) {
            bf16x8 af[4];
#pragma unroll
            for (int i = 0; i < 4; ++i)
                af[i] = *reinterpret_cast<const bf16x8*>(
                    &Bs[buf][(i * 16 + l15) * 512 + (((t8 * 4 + lg) * 16) ^ swz)]);
#pragma unroll
            for (int i = 0; i < 4; ++i)
#pragma unroll
                for (int j = 0; j < 4; ++j)
                    acc[i][j] = __builtin_amdgcn_mfma_f32_16x16x32_bf16(
                        af[i], zreg[j][t8], acc[i][j], 0, 0, 0);
        }

        // ---- epilogue: in-register top-2 per z-row over this 64-col tile ----
        const int c0 = c0q + t * 64;
        const unsigned cb = (unsigned)((t & 1) * 64 + lg * 4);
        f32x4 e2v[4];
#pragma unroll
        for (int i = 0; i < 4; ++i)
            e2v[i] = *reinterpret_cast<const f32x4*>(e2p + c0 + i * 16 + lg * 4);
#pragma unroll
        for (int j = 0; j < 4; ++j) {
            unsigned c1 = 0xFFFFFFFFu, c2 = 0xFFFFFFFFu;
#pragma unroll
            for (int i = 0; i < 4; ++i) {
#pragma unroll
                for (int qp = 0; qp < 2; ++qp) {
                    float va = fmaf(-2.f, acc[i][j][qp * 2],     e2v[i][qp * 2]);
                    float vb = fmaf(-2.f, acc[i][j][qp * 2 + 1], e2v[i][qp * 2 + 1]);
                    unsigned ka = (__float_as_uint(va) & 0xFFFFFF80u) | (cb + i * 16 + qp * 2);
                    unsigned kb = (__float_as_uint(vb) & 0xFFFFFF80u) | (cb + i * 16 + qp * 2 + 1);
                    unsigned lo = umn(ka, kb), hi = umx(ka, kb);
                    unsigned mx = umx(c1, lo);
                    c1 = umn(c1, lo);
                    c2 = umn(umn(c2, hi), mx);
                }
            }
#pragma unroll
            for (int off = 16; off < 64; off <<= 1) {    // merge across lg groups
                unsigned o1 = (unsigned)__shfl_xor((int)c1, off);
                unsigned o2 = (unsigned)__shfl_xor((int)c2, off);
                unsigned mx = umx(c1, o1);
                c1 = umn(c1, o1);
                c2 = umn(umn(c2, o2), mx);
            }
            if ((t & 1) == 0) {
                rk1[j] = c1; rk2[j] = c2;
            } else {
                unsigned M1 = umn(rk1[j], c1);
                unsigned M2 = umn(umn(rk2[j], c2), umx(rk1[j], c1));
                if (lg == 0) {
                    float m1f = __uint_as_float(M1 & 0xFFFFFF80u) - 0.5f;  // <= true min
                    float m2f = __uint_as_float(M2 & 0xFFFFFF80u) - 0.5f;  // <= true 2nd
                    wsp[(size_t)(wr0 + j * 16 + l15) * 64 + (q * 16 + (t >> 1))] =
                        make_uint2(__float_as_uint(m1f),
                                   (bf16_rd(m2f) << 16) | (M1 & 0x7Fu));
                }
            }
        }
    }
}

// ---------- pass 2: candidate-column exact np re-eval + argmin + gather (proven) ----------
__global__ __launch_bounds__(256) void vq_pass2(
        const float* __restrict__ z, const float* __restrict__ e,
        const float* __restrict__ z2, const float* __restrict__ e2,
        const uint2* __restrict__ wsp, float* __restrict__ out) {
    __shared__ __align__(16) float zrow[4][ED];
    const int wid = threadIdx.x >> 6, lane = threadIdx.x & 63;
    const int r = blockIdx.x * 4 + wid;

    *reinterpret_cast<float4*>(&zrow[wid][lane * 4]) =
        *reinterpret_cast<const float4*>(z + (size_t)r * ED + lane * 4);
    __syncthreads();

    const float z2r = z2[r];
    uint2 p = wsp[(size_t)r * 64 + lane];                 // one 128-chunk per lane
    float m1 = __uint_as_float(p.x);
    int   i8 = (int)(p.y & 0xFFu);
    float m2 = __uint_as_float(p.y & 0xFFFF0000u);        // conservative (<= true m2)

    float rmn = m1;
#pragma unroll
    for (int off = 1; off < 64; off <<= 1) rmn = fminf(rmn, __shfl_xor(rmn, off));
    const float thr = rmn + DELTA;

    const bool cF = (m2 <= thr);
    const bool cS = (m1 <= thr) && !cF;
    unsigned long long bS = __ballot(cS);
    unsigned long long bF = __ballot(cF);

    float bd = 3.4e38f;
    int   bc = NE;

    // ---- single-column candidates: batch into lanes, one col per lane ----
    int myCol = -1;
    int cnt = 0;
    unsigned long long m = bS;
    while (true) {
        bool flush = (m == 0) || (cnt == 64);
        if (flush) {
            if (cnt > 0) {
                int ecol = (myCol >= 0) ? myCol : 0;
                const float* ec = e + (size_t)ecol * ED;
                float a0 = 0.f, a1 = 0.f, a2 = 0.f, a3 = 0.f;
#pragma unroll 8
                for (int t = 0; t < 64; ++t) {
                    float4 ev = *reinterpret_cast<const float4*>(ec + 4 * t);
                    float4 zv = *reinterpret_cast<const float4*>(&zrow[wid][4 * t]);
                    a0 = __fadd_rn(a0, __fmul_rn(zv.x, ev.x));
                    a1 = __fadd_rn(a1, __fmul_rn(zv.y, ev.y));
                    a2 = __fadd_rn(a2, __fmul_rn(zv.z, ev.z));
                    a3 = __fadd_rn(a3, __fmul_rn(zv.w, ev.w));
                }
                float s = __fadd_rn(__fadd_rn(a0, a1), __fadd_rn(a2, a3));
                float d = __fsub_rn(__fadd_rn(z2r, e2[ecol]), __fmul_rn(2.0f, s));
                if (myCol >= 0 && (d < bd || (d == bd && ecol < bc))) { bd = d; bc = ecol; }
                myCol = -1; cnt = 0;
            }
            if (m == 0) break;
        }
        int ch = __builtin_ctzll(m); m &= m - 1;
        int col = ch * 128 + __shfl(i8, ch);
        if (lane == cnt) myCol = col;
        ++cnt;
    }

    // ---- full-chunk candidates (rare; covers exact d'-ties automatically) ----
    m = bF;
    while (m) {
        int ch = __builtin_ctzll(m); m &= m - 1;
#pragma unroll
        for (int hh = 0; hh < 2; ++hh) {
            int col = ch * 128 + hh * 64 + lane;
            const float* ec = e + (size_t)col * ED;
            float a0 = 0.f, a1 = 0.f, a2 = 0.f, a3 = 0.f;
#pragma unroll 8
            for (int t = 0; t < 64; ++t) {
                float4 ev = *reinterpret_cast<const float4*>(ec + 4 * t);
                float4 zv = *reinterpret_cast<const float4*>(&zrow[wid][4 * t]);
                a0 = __fadd_rn(a0, __fmul_rn(zv.x, ev.x));
                a1 = __fadd_rn(a1, __fmul_rn(zv.y, ev.y));
                a2 = __fadd_rn(a2, __fmul_rn(zv.z, ev.z));
                a3 = __fadd_rn(a3, __fmul_rn(zv.w, ev.w));
            }
            float s = __fadd_rn(__fadd_rn(a0, a1), __fadd_rn(a2, a3));
            float d = __fsub_rn(__fadd_rn(z2r, e2[col]), __fmul_rn(2.0f, s));
            if (d < bd || (d == bd && col < bc)) { bd = d; bc = col; }
        }
    }

#pragma unroll
    for (int off = 1; off < 64; off <<= 1) {
        float od = __shfl_xor(bd, off);
        int   oc = __shfl_xor(bc, off);
        if (od < bd || (od == bd && oc < bc)) { bd = od; bc = oc; }
    }
    if (lane == 0) out[(size_t)BS * ED + r] = (float)bc;
    *reinterpret_cast<float4*>(out + (size_t)r * ED + lane * 4) =
        *reinterpret_cast<const float4*>(e + (size_t)bc * ED + lane * 4);
}

extern "C" void kernel_launch(void* const* d_in, const int* in_sizes, int n_in,
                              void* d_out, int out_size, void* d_ws, size_t ws_size,
                              hipStream_t stream) {
    const float* z = (const float*)d_in[0];
    const float* e = (const float*)d_in[1];
    float* out   = (float*)d_out;
    float* e2np  = (float*)d_ws;                     // 8192 f32 (exact, for pass2)
    float* e2p5  = e2np + NE;                        // 8192 f32 (+0.5, for pass1 keys)
    float* z2np  = e2p5 + NE;                        // 32768 f32
    uint2* wsp   = (uint2*)(z2np + BS);              // 32768 x 64 x 8B = 16 MB
    short* eb    = (short*)(wsp + (size_t)BS * 64);  // 8192 x 256 bf16 = 4 MB

    hipLaunchKernelGGL(sq_np_kernel, dim3(NE / 32), dim3(256), 0, stream, e, e2np, e2p5);
    hipLaunchKernelGGL(sq_np_kernel, dim3(BS / 32), dim3(256), 0, stream, z, z2np, (float*)nullptr);
    hipLaunchKernelGGL(cvt_bf16_kernel, dim3(NE * ED / 8 / 256), dim3(256), 0, stream, e, eb);
    hipLaunchKernelGGL(vq_pass1, dim3(512), dim3(256), 0, stream,
                       z, (const char*)eb, e2p5, wsp);
    hipLaunchKernelGGL(vq_pass2, dim3(BS / 4), dim3(256), 0, stream, z, e, z2np, e2np, wsp, out);
}

// Round 10
// 416.115 us; speedup vs baseline: 1.0050x; 1.0050x over previous
//
#include <hip/hip_runtime.h>

constexpr int NE = 8192;
constexpr int ED = 256;
constexpr int BS = 32768;
constexpr float DELTA = 4e-4f;   // >> 2*(bf16-MFMA err) + np-grid + key-quantization (~7.6e-6)

typedef short bf16x8 __attribute__((ext_vector_type(8)));
typedef float f32x4 __attribute__((ext_vector_type(4)));

__device__ __forceinline__ short f2bf(float f) {            // RNE f32 -> bf16
    unsigned u = __float_as_uint(f);
    u = u + 0x7FFFu + ((u >> 16) & 1u);
    return (short)(u >> 16);
}
__device__ __forceinline__ unsigned bf16_rd(float x) {      // round toward -inf -> bf16 bits
    unsigned u = __float_as_uint(x);
    unsigned h = u >> 16;
    if ((u & 0x80000000u) && (u & 0xFFFFu)) ++h;
    return h;
}
__device__ __forceinline__ unsigned umn(unsigned a, unsigned b) { return a < b ? a : b; }
__device__ __forceinline__ unsigned umx(unsigned a, unsigned b) { return a > b ? a : b; }

// ---------- np-exact pairwise ||row||^2 (verified bit-exact vs np.sum in R2) ----------
// out5 (optional): +0.5 biased copy for pass1 keys.
__global__ void sq_np_kernel(const float* __restrict__ a, float* __restrict__ out,
                             float* __restrict__ out5) {
    int gtid = blockIdx.x * blockDim.x + threadIdx.x;
    int wave = gtid >> 6;
    int lane = threadIdx.x & 63;
    int sub  = lane & 7;
    int row  = wave * 8 + (lane >> 3);
    const float* p = a + (size_t)row * ED;
    float b0 = 0.f, b1 = 0.f;
#pragma unroll
    for (int t = 0; t < 16; ++t) { float v = p[8 * t + sub];       b0 = __fadd_rn(b0, __fmul_rn(v, v)); }
#pragma unroll
    for (int t = 0; t < 16; ++t) { float v = p[128 + 8 * t + sub]; b1 = __fadd_rn(b1, __fmul_rn(v, v)); }
    b0 = __fadd_rn(b0, __shfl_xor(b0, 1));
    b0 = __fadd_rn(b0, __shfl_xor(b0, 2));
    b0 = __fadd_rn(b0, __shfl_xor(b0, 4));
    b1 = __fadd_rn(b1, __shfl_xor(b1, 1));
    b1 = __fadd_rn(b1, __shfl_xor(b1, 2));
    b1 = __fadd_rn(b1, __shfl_xor(b1, 4));
    float tot = __fadd_rn(b0, b1);
    if (sub == 0) {
        out[row] = tot;
        if (out5) out5[row] = tot + 0.5f;
    }
}

// ---------- convert e (f32) -> eb (bf16), row-major, once ----------
__global__ void cvt_bf16_kernel(const float* __restrict__ a, short* __restrict__ o) {
    int i = blockIdx.x * blockDim.x + threadIdx.x;     // one per 8 elements
    const float4* p = reinterpret_cast<const float4*>(a + (size_t)i * 8);
    float4 v0 = p[0], v1 = p[1];
    bf16x8 h;
    h[0] = f2bf(v0.x); h[1] = f2bf(v0.y); h[2] = f2bf(v0.z); h[3] = f2bf(v0.w);
    h[4] = f2bf(v1.x); h[5] = f2bf(v1.y); h[6] = f2bf(v1.z); h[7] = f2bf(v1.w);
    *reinterpret_cast<bf16x8*>(o + (size_t)i * 8) = h;
}

// ---------- pass 1: LDS-free. D = e·z^T, z full-K in regs, B-frags from L2 ----------
// 4 waves x 64 z-rows = 256 rows/block; col-quarter (2048 cols) = 32 tiles of 64.
// acc: col(lane&15) = z-row, row(lg*4+reg) = e-col. i-halved acc (2 halves of 32 cols).
__device__ __forceinline__ void load_step(bf16x8 (&b)[2][2], const char* abase, int S) {
    int t_ = S >> 3;
    int s_ = S & 7;
    int i0 = (s_ >> 2) << 1;             // col-subtile base of this half
    int tp = (s_ & 3) << 1;              // t8 pair base
    size_t o = (size_t)t_ * 32768 + (size_t)i0 * 8192 + (size_t)tp * 64;
    b[0][0] = *reinterpret_cast<const bf16x8*>(abase + o);
    b[0][1] = *reinterpret_cast<const bf16x8*>(abase + o + 64);
    b[1][0] = *reinterpret_cast<const bf16x8*>(abase + o + 8192);
    b[1][1] = *reinterpret_cast<const bf16x8*>(abase + o + 8192 + 64);
}

__global__ __launch_bounds__(256, 2) void vq_pass1(
        const float* __restrict__ z, const char* __restrict__ eb,
        const float* __restrict__ e2p, uint2* __restrict__ wsp) {
    const int tid  = threadIdx.x;
    const int wid  = tid >> 6, lane = tid & 63;
    const int l15  = lane & 15, lg = lane >> 4;
    const int kblk = blockIdx.x;
    const int rg   = (kblk & 7) | ((kblk >> 5) << 3);   // row-group: quarters share XCD
    const int q    = (kblk >> 3) & 3;
    const int c0q  = q * 2048;
    const int wr0  = rg * 256 + wid * 64;

    // ---- z rows -> registers (bf16), 64 rows/wave, full K ----
    bf16x8 zreg[4][8];
#pragma unroll
    for (int j = 0; j < 4; ++j) {
        const float* zr = z + (size_t)(wr0 + j * 16 + l15) * ED + lg * 8;
#pragma unroll
        for (int t8 = 0; t8 < 8; ++t8) {
            float4 v0 = *reinterpret_cast<const float4*>(zr + t8 * 32);
            float4 v1 = *reinterpret_cast<const float4*>(zr + t8 * 32 + 4);
            bf16x8 h;
            h[0] = f2bf(v0.x); h[1] = f2bf(v0.y); h[2] = f2bf(v0.z); h[3] = f2bf(v0.w);
            h[4] = f2bf(v1.x); h[5] = f2bf(v1.y); h[6] = f2bf(v1.z); h[7] = f2bf(v1.w);
            zreg[j][t8] = h;
        }
    }

    // per-lane global base into eb for B fragments (4 lanes/64B line: coalesced)
    const char* abase = eb + (size_t)(c0q + l15) * 512 + lg * 16;

    bf16x8 buf[2][2][2];                 // ping-pong, [i2][tt]
    load_step(buf[0], abase, 0);

    unsigned rk1[4], rk2[4], c1t[4], c2t[4];

    for (int t = 0; t < 32; ++t) {
        const int c0 = c0q + t * 64;
        f32x4 acc[2][4];
#pragma unroll
        for (int s = 0; s < 8; ++s) {
            if ((s & 3) == 0) {
#pragma unroll
                for (int i2 = 0; i2 < 2; ++i2)
#pragma unroll
                    for (int j = 0; j < 4; ++j) acc[i2][j] = (f32x4){0.f, 0.f, 0.f, 0.f};
            }
            int Sn = t * 8 + s + 1;
            Sn = Sn > 255 ? 255 : Sn;    // clamp: tail reload, never consumed
            load_step(buf[(s + 1) & 1], abase, Sn);
#pragma unroll
            for (int tt = 0; tt < 2; ++tt)
#pragma unroll
                for (int i2 = 0; i2 < 2; ++i2)
#pragma unroll
                    for (int j = 0; j < 4; ++j)
                        acc[i2][j] = __builtin_amdgcn_mfma_f32_16x16x32_bf16(
                            buf[s & 1][i2][tt], zreg[j][(s & 3) * 2 + tt],
                            acc[i2][j], 0, 0, 0);

            if ((s & 3) == 3) {          // half-epilogue: h = s>>2, cols i0*16..i0*16+31
                const int h = s >> 2, i0 = h * 2;
                f32x4 e2a = *reinterpret_cast<const f32x4*>(e2p + c0 + i0 * 16 + lg * 4);
                f32x4 e2b = *reinterpret_cast<const f32x4*>(e2p + c0 + i0 * 16 + 16 + lg * 4);
                const unsigned cb = (unsigned)((t & 1) * 64 + lg * 4);
#pragma unroll
                for (int j = 0; j < 4; ++j) {
                    unsigned c1 = 0xFFFFFFFFu, c2 = 0xFFFFFFFFu;
#pragma unroll
                    for (int qp = 0; qp < 2; ++qp) {
                        float va = fmaf(-2.f, acc[0][j][qp * 2],     e2a[qp * 2]);
                        float vb = fmaf(-2.f, acc[0][j][qp * 2 + 1], e2a[qp * 2 + 1]);
                        unsigned ka = (__float_as_uint(va) & 0xFFFFFF80u) | (cb + i0 * 16 + qp * 2);
                        unsigned kb = (__float_as_uint(vb) & 0xFFFFFF80u) | (cb + i0 * 16 + qp * 2 + 1);
                        unsigned lo = umn(ka, kb), hi = umx(ka, kb);
                        unsigned mx = umx(c1, lo);
                        c1 = umn(c1, lo);
                        c2 = umn(umn(c2, hi), mx);
                        va = fmaf(-2.f, acc[1][j][qp * 2],     e2b[qp * 2]);
                        vb = fmaf(-2.f, acc[1][j][qp * 2 + 1], e2b[qp * 2 + 1]);
                        ka = (__float_as_uint(va) & 0xFFFFFF80u) | (cb + (i0 + 1) * 16 + qp * 2);
                        kb = (__float_as_uint(vb) & 0xFFFFFF80u) | (cb + (i0 + 1) * 16 + qp * 2 + 1);
                        lo = umn(ka, kb); hi = umx(ka, kb);
                        mx = umx(c1, lo);
                        c1 = umn(c1, lo);
                        c2 = umn(umn(c2, hi), mx);
                    }
                    if (h == 0) {
                        c1t[j] = c1; c2t[j] = c2;
                    } else {
                        unsigned mxh = umx(c1t[j], c1);
                        c1 = umn(c1t[j], c1);
                        c2 = umn(umn(c2t[j], c2), mxh);
#pragma unroll
                        for (int off = 16; off < 64; off <<= 1) {   // merge lg groups
                            unsigned o1 = (unsigned)__shfl_xor((int)c1, off);
                            unsigned o2 = (unsigned)__shfl_xor((int)c2, off);
                            unsigned mx2 = umx(c1, o1);
                            c1 = umn(c1, o1);
                            c2 = umn(umn(c2, o2), mx2);
                        }
                        if ((t & 1) == 0) {
                            rk1[j] = c1; rk2[j] = c2;
                        } else {
                            unsigned M1 = umn(rk1[j], c1);
                            unsigned M2 = umn(umn(rk2[j], c2), umx(rk1[j], c1));
                            if (lg == 0) {
                                float m1f = __uint_as_float(M1 & 0xFFFFFF80u) - 0.5f;  // <= true min
                                float m2f = __uint_as_float(M2 & 0xFFFFFF80u) - 0.5f;  // <= true 2nd
                                wsp[(size_t)(wr0 + j * 16 + l15) * 64 + (q * 16 + (t >> 1))] =
                                    make_uint2(__float_as_uint(m1f),
                                               (bf16_rd(m2f) << 16) | (M1 & 0x7Fu));
                            }
                        }
                    }
                }
            }
        }
    }
}

// ---------- pass 2: candidate-column exact np re-eval + argmin + gather (proven) ----------
__global__ __launch_bounds__(256) void vq_pass2(
        const float* __restrict__ z, const float* __restrict__ e,
        const float* __restrict__ z2, const float* __restrict__ e2,
        const uint2* __restrict__ wsp, float* __restrict__ out) {
    __shared__ __align__(16) float zrow[4][ED];
    const int wid = threadIdx.x >> 6, lane = threadIdx.x & 63;
    const int r = blockIdx.x * 4 + wid;

    *reinterpret_cast<float4*>(&zrow[wid][lane * 4]) =
        *reinterpret_cast<const float4*>(z + (size_t)r * ED + lane * 4);
    __syncthreads();

    const float z2r = z2[r];
    uint2 p = wsp[(size_t)r * 64 + lane];                 // one 128-chunk per lane
    float m1 = __uint_as_float(p.x);
    int   i8 = (int)(p.y & 0xFFu);
    float m2 = __uint_as_float(p.y & 0xFFFF0000u);        // conservative (<= true m2)

    float rmn = m1;
#pragma unroll
    for (int off = 1; off < 64; off <<= 1) rmn = fminf(rmn, __shfl_xor(rmn, off));
    const float thr = rmn + DELTA;

    const bool cF = (m2 <= thr);
    const bool cS = (m1 <= thr) && !cF;
    unsigned long long bS = __ballot(cS);
    unsigned long long bF = __ballot(cF);

    float bd = 3.4e38f;
    int   bc = NE;

    // ---- single-column candidates: batch into lanes, one col per lane ----
    int myCol = -1;
    int cnt = 0;
    unsigned long long m = bS;
    while (true) {
        bool flush = (m == 0) || (cnt == 64);
        if (flush) {
            if (cnt > 0) {
                int ecol = (myCol >= 0) ? myCol : 0;
                const float* ec = e + (size_t)ecol * ED;
                float a0 = 0.f, a1 = 0.f, a2 = 0.f, a3 = 0.f;
#pragma unroll 8
                for (int t = 0; t < 64; ++t) {
                    float4 ev = *reinterpret_cast<const float4*>(ec + 4 * t);
                    float4 zv = *reinterpret_cast<const float4*>(&zrow[wid][4 * t]);
                    a0 = __fadd_rn(a0, __fmul_rn(zv.x, ev.x));
                    a1 = __fadd_rn(a1, __fmul_rn(zv.y, ev.y));
                    a2 = __fadd_rn(a2, __fmul_rn(zv.z, ev.z));
                    a3 = __fadd_rn(a3, __fmul_rn(zv.w, ev.w));
                }
                float s = __fadd_rn(__fadd_rn(a0, a1), __fadd_rn(a2, a3));
                float d = __fsub_rn(__fadd_rn(z2r, e2[ecol]), __fmul_rn(2.0f, s));
                if (myCol >= 0 && (d < bd || (d == bd && ecol < bc))) { bd = d; bc = ecol; }
                myCol = -1; cnt = 0;
            }
            if (m == 0) break;
        }
        int ch = __builtin_ctzll(m); m &= m - 1;
        int col = ch * 128 + __shfl(i8, ch);
        if (lane == cnt) myCol = col;
        ++cnt;
    }

    // ---- full-chunk candidates (rare; covers exact d'-ties automatically) ----
    m = bF;
    while (m) {
        int ch = __builtin_ctzll(m); m &= m - 1;
#pragma unroll
        for (int hh = 0; hh < 2; ++hh) {
            int col = ch * 128 + hh * 64 + lane;
            const float* ec = e + (size_t)col * ED;
            float a0 = 0.f, a1 = 0.f, a2 = 0.f, a3 = 0.f;
#pragma unroll 8
            for (int t = 0; t < 64; ++t) {
                float4 ev = *reinterpret_cast<const float4*>(ec + 4 * t);
                float4 zv = *reinterpret_cast<const float4*>(&zrow[wid][4 * t]);
                a0 = __fadd_rn(a0, __fmul_rn(zv.x, ev.x));
                a1 = __fadd_rn(a1, __fmul_rn(zv.y, ev.y));
                a2 = __fadd_rn(a2, __fmul_rn(zv.z, ev.z));
                a3 = __fadd_rn(a3, __fmul_rn(zv.w, ev.w));
            }
            float s = __fadd_rn(__fadd_rn(a0, a1), __fadd_rn(a2, a3));
            float d = __fsub_rn(__fadd_rn(z2r, e2[col]), __fmul_rn(2.0f, s));
            if (d < bd || (d == bd && col < bc)) { bd = d; bc = col; }
        }
    }

#pragma unroll
    for (int off = 1; off < 64; off <<= 1) {
        float od = __shfl_xor(bd, off);
        int   oc = __shfl_xor(bc, off);
        if (od < bd || (od == bd && oc < bc)) { bd = od; bc = oc; }
    }
    if (lane == 0) out[(size_t)BS * ED + r] = (float)bc;
    *reinterpret_cast<float4*>(out + (size_t)r * ED + lane * 4) =
        *reinterpret_cast<const float4*>(e + (size_t)bc * ED + lane * 4);
}

extern "C" void kernel_launch(void* const* d_in, const int* in_sizes, int n_in,
                              void* d_out, int out_size, void* d_ws, size_t ws_size,
                              hipStream_t stream) {
    const float* z = (const float*)d_in[0];
    const float* e = (const float*)d_in[1];
    float* out   = (float*)d_out;
    float* e2np  = (float*)d_ws;                     // 8192 f32 (exact, for pass2)
    float* e2p5  = e2np + NE;                        // 8192 f32 (+0.5, for pass1 keys)
    float* z2np  = e2p5 + NE;                        // 32768 f32
    uint2* wsp   = (uint2*)(z2np + BS);              // 32768 x 64 x 8B = 16 MB
    short* eb    = (short*)(wsp + (size_t)BS * 64);  // 8192 x 256 bf16 = 4 MB

    hipLaunchKernelGGL(sq_np_kernel, dim3(NE / 32), dim3(256), 0, stream, e, e2np, e2p5);
    hipLaunchKernelGGL(sq_np_kernel, dim3(BS / 32), dim3(256), 0, stream, z, z2np, (float*)nullptr);
    hipLaunchKernelGGL(cvt_bf16_kernel, dim3(NE * ED / 8 / 256), dim3(256), 0, stream, e, eb);
    hipLaunchKernelGGL(vq_pass1, dim3(512), dim3(256), 0, stream,
                       z, (const char*)eb, e2p5, wsp);
    hipLaunchKernelGGL(vq_pass2, dim3(BS / 4), dim3(256), 0, stream, z, e, z2np, e2np, wsp, out);
}

// Round 11
// 290.065 us; speedup vs baseline: 1.4418x; 1.4346x over previous
//
#include <hip/hip_runtime.h>

constexpr int NE = 8192;
constexpr int ED = 256;
constexpr int BS = 32768;
constexpr float DELTA = 4e-4f;   // >> bf16-MFMA err + key quant (7.6e-6) + e2-fusion (1.3e-9)

typedef short bf16x8 __attribute__((ext_vector_type(8)));
typedef float f32x4 __attribute__((ext_vector_type(4)));

constexpr size_t WSTR = (size_t)NE * 64;   // ebT k-window stride (512 KB)

__device__ __forceinline__ short f2bf(float f) {            // RNE f32 -> bf16
    unsigned u = __float_as_uint(f);
    u = u + 0x7FFFu + ((u >> 16) & 1u);
    return (short)(u >> 16);
}
__device__ __forceinline__ unsigned bf16_rd(float x) {      // round toward -inf -> bf16 bits
    unsigned u = __float_as_uint(x);
    unsigned h = u >> 16;
    if ((u & 0x80000000u) && (u & 0xFFFFu)) ++h;
    return h;
}
__device__ __forceinline__ unsigned umn(unsigned a, unsigned b) { return a < b ? a : b; }
__device__ __forceinline__ unsigned umx(unsigned a, unsigned b) { return a > b ? a : b; }

// ---------- np-exact pairwise ||row||^2 (verified bit-exact vs np.sum in R2) ----------
__global__ void sq_np_kernel(const float* __restrict__ a, float* __restrict__ out) {
    int gtid = blockIdx.x * blockDim.x + threadIdx.x;
    int wave = gtid >> 6;
    int lane = threadIdx.x & 63;
    int sub  = lane & 7;
    int row  = wave * 8 + (lane >> 3);
    const float* p = a + (size_t)row * ED;
    float b0 = 0.f, b1 = 0.f;
#pragma unroll
    for (int t = 0; t < 16; ++t) { float v = p[8 * t + sub];       b0 = __fadd_rn(b0, __fmul_rn(v, v)); }
#pragma unroll
    for (int t = 0; t < 16; ++t) { float v = p[128 + 8 * t + sub]; b1 = __fadd_rn(b1, __fmul_rn(v, v)); }
    b0 = __fadd_rn(b0, __shfl_xor(b0, 1));
    b0 = __fadd_rn(b0, __shfl_xor(b0, 2));
    b0 = __fadd_rn(b0, __shfl_xor(b0, 4));
    b1 = __fadd_rn(b1, __shfl_xor(b1, 1));
    b1 = __fadd_rn(b1, __shfl_xor(b1, 2));
    b1 = __fadd_rn(b1, __shfl_xor(b1, 4));
    if (sub == 0) out[row] = __fadd_rn(b0, b1);
}

// ---------- e (f32) -> ebT (bf16, k-major): [w][col][64B], w=k-window of 32 ----------
__global__ void cvt_ebT_kernel(const float* __restrict__ e, char* __restrict__ ebT) {
    int i = blockIdx.x * blockDim.x + threadIdx.x;     // one per 16B unit (262144)
    int c = i >> 5;                                    // e-row (col in GEMM)
    int u = i & 31;
    int w = u >> 2, lg = u & 3;
    const float* p = e + (size_t)c * ED + w * 32 + lg * 8;
    float4 v0 = *reinterpret_cast<const float4*>(p);
    float4 v1 = *reinterpret_cast<const float4*>(p + 4);
    bf16x8 h;
    h[0] = f2bf(v0.x); h[1] = f2bf(v0.y); h[2] = f2bf(v0.z); h[3] = f2bf(v0.w);
    h[4] = f2bf(v1.x); h[5] = f2bf(v1.y); h[6] = f2bf(v1.z); h[7] = f2bf(v1.w);
    *reinterpret_cast<bf16x8*>(ebT + (size_t)w * WSTR + (size_t)c * 64 + lg * 16) = h;
}

// ---------- w=8 slot: [bf16(-e2/2), 0 x31] per col (fused e2 term) ----------
__global__ void e2slot_kernel(const float* __restrict__ e2, char* __restrict__ ebT) {
    int c = blockIdx.x * blockDim.x + threadIdx.x;
    bf16x8 h = {};
    h[0] = f2bf(e2[c] * -0.5f);
    bf16x8 zz = {};
    char* p = ebT + 8 * WSTR + (size_t)c * 64;
    *reinterpret_cast<bf16x8*>(p)      = h;
    *reinterpret_cast<bf16x8*>(p + 16) = zz;
    *reinterpret_cast<bf16x8*>(p + 32) = zz;
    *reinterpret_cast<bf16x8*>(p + 48) = zz;
}

// ---------- pass 1: LDS-free, coalesced k-major B loads, e2 fused into MFMA ----------
// 4 waves x 64 z-rows = 256 rows/block; col-quarter (2048) = 32 tiles of 64.
// acc = dot - e2/2 ; key v = fmaf(-2, acc, 0.5) = d' + 0.5 > 0.
__device__ __forceinline__ void load_step(bf16x8 (&b)[2][2], const char* abase, int S) {
    int t_ = S >> 3, s_ = S & 7;
    size_t colbyte = (size_t)((t_ << 6) + ((s_ >> 2) << 5)) << 6;   // (t*64+h*32)*64
    const char* p = abase + (size_t)((s_ & 3) << 1) * WSTR + colbyte;
    b[0][0] = *reinterpret_cast<const bf16x8*>(p);
    b[0][1] = *reinterpret_cast<const bf16x8*>(p + WSTR);
    b[1][0] = *reinterpret_cast<const bf16x8*>(p + 1024);
    b[1][1] = *reinterpret_cast<const bf16x8*>(p + WSTR + 1024);
}

__global__ __launch_bounds__(256, 2) void vq_pass1(
        const float* __restrict__ z, const char* __restrict__ ebT,
        uint2* __restrict__ wsp) {
    const int tid  = threadIdx.x;
    const int wid  = tid >> 6, lane = tid & 63;
    const int l15  = lane & 15, lg = lane >> 4;
    const int kblk = blockIdx.x;
    const int rg   = (kblk & 7) | ((kblk >> 5) << 3);   // row-group: quarters share XCD
    const int q    = (kblk >> 3) & 3;
    const int c0q  = q * 2048;
    const int wr0  = rg * 256 + wid * 64;

    // ---- z rows -> registers (bf16), 64 rows/wave, full K ----
    bf16x8 zreg[4][8];
#pragma unroll
    for (int j = 0; j < 4; ++j) {
        const float* zr = z + (size_t)(wr0 + j * 16 + l15) * ED + lg * 8;
#pragma unroll
        for (int t8 = 0; t8 < 8; ++t8) {
            float4 v0 = *reinterpret_cast<const float4*>(zr + t8 * 32);
            float4 v1 = *reinterpret_cast<const float4*>(zr + t8 * 32 + 4);
            bf16x8 h;
            h[0] = f2bf(v0.x); h[1] = f2bf(v0.y); h[2] = f2bf(v0.z); h[3] = f2bf(v0.w);
            h[4] = f2bf(v1.x); h[5] = f2bf(v1.y); h[6] = f2bf(v1.z); h[7] = f2bf(v1.w);
            zreg[j][t8] = h;
        }
    }
    bf16x8 zE = {};                      // z-side k=256 slot: 1.0 at first k
    if (lg == 0) zE[0] = (short)0x3F80;

    const char* abase = ebT + (size_t)(c0q + l15) * 64 + lg * 16;

    bf16x8 buf[2][2][2];                 // ping-pong [i2][tt]
    bf16x8 bufE[2];
    load_step(buf[0], abase, 0);

    unsigned rk1[4], rk2[4];

    for (int t = 0; t < 32; ++t) {
        f32x4 acc[2][4];
#pragma unroll
        for (int s = 0; s < 8; ++s) {
            if ((s & 3) == 0) {
#pragma unroll
                for (int i2 = 0; i2 < 2; ++i2)
#pragma unroll
                    for (int j = 0; j < 4; ++j) acc[i2][j] = (f32x4){0.f, 0.f, 0.f, 0.f};
                size_t colbyte = (size_t)((t << 6) + ((s >> 2) << 5)) << 6;
                bufE[0] = *reinterpret_cast<const bf16x8*>(abase + 8 * WSTR + colbyte);
                bufE[1] = *reinterpret_cast<const bf16x8*>(abase + 8 * WSTR + colbyte + 1024);
            }
            int Sn = t * 8 + s + 1;
            Sn = Sn > 255 ? 255 : Sn;    // tail: reload, never consumed
            load_step(buf[(s + 1) & 1], abase, Sn);
#pragma unroll
            for (int tt = 0; tt < 2; ++tt)
#pragma unroll
                for (int i2 = 0; i2 < 2; ++i2)
#pragma unroll
                    for (int j = 0; j < 4; ++j)
                        acc[i2][j] = __builtin_amdgcn_mfma_f32_16x16x32_bf16(
                            buf[s & 1][i2][tt], zreg[j][(s & 3) * 2 + tt],
                            acc[i2][j], 0, 0, 0);

            if ((s & 3) == 3) {          // half-epilogue: cols i0*16 .. i0*16+31
                const int i0 = (s >> 2) * 2;
#pragma unroll
                for (int i2 = 0; i2 < 2; ++i2)      // fused e2 term (w=8)
#pragma unroll
                    for (int j = 0; j < 4; ++j)
                        acc[i2][j] = __builtin_amdgcn_mfma_f32_16x16x32_bf16(
                            bufE[i2], zE, acc[i2][j], 0, 0, 0);

                const unsigned cb = (unsigned)((t & 1) * 64 + lg * 4);
#pragma unroll
                for (int j = 0; j < 4; ++j) {
                    unsigned c1 = 0xFFFFFFFFu, c2 = 0xFFFFFFFFu;
#pragma unroll
                    for (int qp = 0; qp < 2; ++qp) {
                        float va = fmaf(-2.f, acc[0][j][qp * 2],     0.5f);
                        float vb = fmaf(-2.f, acc[0][j][qp * 2 + 1], 0.5f);
                        unsigned ka = (__float_as_uint(va) & 0xFFFFFF80u) | (cb + i0 * 16 + qp * 2);
                        unsigned kb = (__float_as_uint(vb) & 0xFFFFFF80u) | (cb + i0 * 16 + qp * 2 + 1);
                        unsigned lo = umn(ka, kb), hi = umx(ka, kb);
                        unsigned mx = umx(c1, lo);
                        c1 = umn(c1, lo);
                        c2 = umn(umn(c2, hi), mx);
                        va = fmaf(-2.f, acc[1][j][qp * 2],     0.5f);
                        vb = fmaf(-2.f, acc[1][j][qp * 2 + 1], 0.5f);
                        ka = (__float_as_uint(va) & 0xFFFFFF80u) | (cb + (i0 + 1) * 16 + qp * 2);
                        kb = (__float_as_uint(vb) & 0xFFFFFF80u) | (cb + (i0 + 1) * 16 + qp * 2 + 1);
                        lo = umn(ka, kb); hi = umx(ka, kb);
                        mx = umx(c1, lo);
                        c1 = umn(c1, lo);
                        c2 = umn(umn(c2, hi), mx);
                    }
                    if (i0 == 0) {       // first half of tile: stash
                        if ((t & 1) == 0) { rk1[j] = c1; rk2[j] = c2; }
                        else {
                            unsigned mxh = umx(rk1[j], c1);
                            rk1[j] = umn(rk1[j], c1);
                            rk2[j] = umn(umn(rk2[j], c2), mxh);
                        }
                    } else {             // second half: merge + lg-reduce (+ write on odd t)
                        unsigned mxh = umx(rk1[j], c1);
                        c1 = umn(rk1[j], c1);
                        c2 = umn(umn(rk2[j], c2), mxh);
                        if ((t & 1) == 0) {
                            rk1[j] = c1; rk2[j] = c2;
                        } else {
#pragma unroll
                            for (int off = 16; off < 64; off <<= 1) {
                                unsigned o1 = (unsigned)__shfl_xor((int)c1, off);
                                unsigned o2 = (unsigned)__shfl_xor((int)c2, off);
                                unsigned mx2 = umx(c1, o1);
                                c1 = umn(c1, o1);
                                c2 = umn(umn(c2, o2), mx2);
                            }
                            if (lg == 0) {
                                float m1f = __uint_as_float(c1 & 0xFFFFFF80u) - 0.5f;  // <= true min
                                float m2f = __uint_as_float(c2 & 0xFFFFFF80u) - 0.5f;  // <= true 2nd
                                wsp[(size_t)(wr0 + j * 16 + l15) * 64 + (q * 16 + (t >> 1))] =
                                    make_uint2(__float_as_uint(m1f),
                                               (bf16_rd(m2f) << 16) | (c1 & 0x7Fu));
                            }
                        }
                    }
                }
            }
        }
    }
}

// ---------- pass 2: candidate-column exact np re-eval + argmin + gather (proven) ----------
__global__ __launch_bounds__(256) void vq_pass2(
        const float* __restrict__ z, const float* __restrict__ e,
        const float* __restrict__ z2, const float* __restrict__ e2,
        const uint2* __restrict__ wsp, float* __restrict__ out) {
    __shared__ __align__(16) float zrow[4][ED];
    const int wid = threadIdx.x >> 6, lane = threadIdx.x & 63;
    const int r = blockIdx.x * 4 + wid;

    *reinterpret_cast<float4*>(&zrow[wid][lane * 4]) =
        *reinterpret_cast<const float4*>(z + (size_t)r * ED + lane * 4);
    __syncthreads();

    const float z2r = z2[r];
    uint2 p = wsp[(size_t)r * 64 + lane];                 // one 128-chunk per lane
    float m1 = __uint_as_float(p.x);
    int   i8 = (int)(p.y & 0xFFu);
    float m2 = __uint_as_float(p.y & 0xFFFF0000u);        // conservative (<= true m2)

    float rmn = m1;
#pragma unroll
    for (int off = 1; off < 64; off <<= 1) rmn = fminf(rmn, __shfl_xor(rmn, off));
    const float thr = rmn + DELTA;

    const bool cF = (m2 <= thr);
    const bool cS = (m1 <= thr) && !cF;
    unsigned long long bS = __ballot(cS);
    unsigned long long bF = __ballot(cF);

    float bd = 3.4e38f;
    int   bc = NE;

    // ---- single-column candidates: batch into lanes, one col per lane ----
    int myCol = -1;
    int cnt = 0;
    unsigned long long m = bS;
    while (true) {
        bool flush = (m == 0) || (cnt == 64);
        if (flush) {
            if (cnt > 0) {
                int ecol = (myCol >= 0) ? myCol : 0;
                const float* ec = e + (size_t)ecol * ED;
                float a0 = 0.f, a1 = 0.f, a2 = 0.f, a3 = 0.f;
#pragma unroll 8
                for (int t = 0; t < 64; ++t) {
                    float4 ev = *reinterpret_cast<const float4*>(ec + 4 * t);
                    float4 zv = *reinterpret_cast<const float4*>(&zrow[wid][4 * t]);
                    a0 = __fadd_rn(a0, __fmul_rn(zv.x, ev.x));
                    a1 = __fadd_rn(a1, __fmul_rn(zv.y, ev.y));
                    a2 = __fadd_rn(a2, __fmul_rn(zv.z, ev.z));
                    a3 = __fadd_rn(a3, __fmul_rn(zv.w, ev.w));
                }
                float s = __fadd_rn(__fadd_rn(a0, a1), __fadd_rn(a2, a3));
                float d = __fsub_rn(__fadd_rn(z2r, e2[ecol]), __fmul_rn(2.0f, s));
                if (myCol >= 0 && (d < bd || (d == bd && ecol < bc))) { bd = d; bc = ecol; }
                myCol = -1; cnt = 0;
            }
            if (m == 0) break;
        }
        int ch = __builtin_ctzll(m); m &= m - 1;
        int col = ch * 128 + __shfl(i8, ch);
        if (lane == cnt) myCol = col;
        ++cnt;
    }

    // ---- full-chunk candidates (rare; covers exact d'-ties automatically) ----
    m = bF;
    while (m) {
        int ch = __builtin_ctzll(m); m &= m - 1;
#pragma unroll
        for (int hh = 0; hh < 2; ++hh) {
            int col = ch * 128 + hh * 64 + lane;
            const float* ec = e + (size_t)col * ED;
            float a0 = 0.f, a1 = 0.f, a2 = 0.f, a3 = 0.f;
#pragma unroll 8
            for (int t = 0; t < 64; ++t) {
                float4 ev = *reinterpret_cast<const float4*>(ec + 4 * t);
                float4 zv = *reinterpret_cast<const float4*>(&zrow[wid][4 * t]);
                a0 = __fadd_rn(a0, __fmul_rn(zv.x, ev.x));
                a1 = __fadd_rn(a1, __fmul_rn(zv.y, ev.y));
                a2 = __fadd_rn(a2, __fmul_rn(zv.z, ev.z));
                a3 = __fadd_rn(a3, __fmul_rn(zv.w, ev.w));
            }
            float s = __fadd_rn(__fadd_rn(a0, a1), __fadd_rn(a2, a3));
            float d = __fsub_rn(__fadd_rn(z2r, e2[col]), __fmul_rn(2.0f, s));
            if (d < bd || (d == bd && col < bc)) { bd = d; bc = col; }
        }
    }

#pragma unroll
    for (int off = 1; off < 64; off <<= 1) {
        float od = __shfl_xor(bd, off);
        int   oc = __shfl_xor(bc, off);
        if (od < bd || (od == bd && oc < bc)) { bd = od; bc = oc; }
    }
    if (lane == 0) out[(size_t)BS * ED + r] = (float)bc;
    *reinterpret_cast<float4*>(out + (size_t)r * ED + lane * 4) =
        *reinterpret_cast<const float4*>(e + (size_t)bc * ED + lane * 4);
}

extern "C" void kernel_launch(void* const* d_in, const int* in_sizes, int n_in,
                              void* d_out, int out_size, void* d_ws, size_t ws_size,
                              hipStream_t stream) {
    const float* z = (const float*)d_in[0];
    const float* e = (const float*)d_in[1];
    float* out   = (float*)d_out;
    float* e2np  = (float*)d_ws;                     // 8192 f32 (exact, for pass2 + e2slot)
    float* z2np  = e2np + NE;                        // 32768 f32
    uint2* wsp   = (uint2*)(z2np + BS);              // 32768 x 64 x 8B = 16 MB
    char*  ebT   = (char*)(wsp + (size_t)BS * 64);   // 9 x 8192 x 64B = 4.5 MB

    hipLaunchKernelGGL(sq_np_kernel, dim3(NE / 32), dim3(256), 0, stream, e, e2np);
    hipLaunchKernelGGL(sq_np_kernel, dim3(BS / 32), dim3(256), 0, stream, z, z2np);
    hipLaunchKernelGGL(cvt_ebT_kernel, dim3(NE * ED / 8 / 256), dim3(256), 0, stream, e, ebT);
    hipLaunchKernelGGL(e2slot_kernel, dim3(NE / 256), dim3(256), 0, stream, e2np, ebT);
    hipLaunchKernelGGL(vq_pass1, dim3(512), dim3(256), 0, stream, z, ebT, wsp);
    hipLaunchKernelGGL(vq_pass2, dim3(BS / 4), dim3(256), 0, stream, z, e, z2np, e2np, wsp, out);
}